// Round 9
// baseline (282.328 us; speedup 1.0000x reference)
//
#include <hip/hip_runtime.h>
#include <stdint.h>

// Problem constants
#define BB 2
#define SS 2048
#define DD 1024
#define HH 16
#define DH 64
#define MM 4096   // BB*SS

typedef __attribute__((ext_vector_type(8))) short short8;
typedef __attribute__((ext_vector_type(4))) float floatx4;
typedef __attribute__((ext_vector_type(16))) float floatx16;
typedef unsigned short u16;

#define MFMA16(a,b,c) __builtin_amdgcn_mfma_f32_16x16x32_bf16((a),(b),(c),0,0,0)
#define MFMA32(a,b,c) __builtin_amdgcn_mfma_f32_32x32x16_bf16((a),(b),(c),0,0,0)

__device__ __forceinline__ u16 f2bf(float f) {
  unsigned u = __float_as_uint(f);
  u += 0x7fffu + ((u >> 16) & 1u);
  return (u16)(u >> 16);
}

__device__ __forceinline__ unsigned cvtpk(float lo, float hi2) {
  unsigned r;
  asm("v_cvt_pk_bf16_f32 %0, %1, %2" : "=v"(r) : "v"(lo), "v"(hi2));
  return r;
}

__device__ __forceinline__ void gll16(const void* g, void* l) {
  __builtin_amdgcn_global_load_lds((const __attribute__((address_space(1))) void*)g,
                                   (__attribute__((address_space(3))) void*)l,
                                   16, 0, 0);
}

// ---------------- prep: sincos table + all fp32->bf16 conversions, one dispatch
__global__ __launch_bounds__(256) void prep(
    const float* __restrict__ q, const float* __restrict__ k, const float* __restrict__ v,
    const float* __restrict__ Wq, const float* __restrict__ Wk,
    const float* __restrict__ Wv, const float* __restrict__ Wo,
    u16* __restrict__ qb, u16* __restrict__ kb, u16* __restrict__ vb,
    u16* __restrict__ wqb, u16* __restrict__ wkb, u16* __restrict__ wvb, u16* __restrict__ wob,
    float2* __restrict__ tab) {
  int bid = blockIdx.x;
  if (bid < 256) {                       // sincos: tab[s*32+j] = (sin(s*inv_j), cos(s*inv_j))
    const int t = bid * 256 + threadIdx.x;
    const int s = t >> 5, j = t & 31;
    const float inv = expf(-(float)j * (0.125f * 2.302585092994046f)); // 10^(-j/8)
    const float a = (float)s * inv;
    tab[t] = make_float2(sinf(a), cosf(a));
    return;
  }
  bid -= 256;
  const float* src;
  u16* dst;
  int x;
  if (bid < 12288) {                     // q,k,v: 3 x 4096 blocks
    const int z = bid >> 12;
    x = bid & 4095;
    src = z == 0 ? q : (z == 1 ? k : v);
    dst = z == 0 ? qb : (z == 1 ? kb : vb);
  } else {                               // weights: 4 x 1024 blocks
    bid -= 12288;
    const int z = bid >> 10;
    x = bid & 1023;
    src = z == 0 ? Wq : (z == 1 ? Wk : (z == 2 ? Wv : Wo));
    dst = z == 0 ? wqb : (z == 1 ? wkb : (z == 2 ? wvb : wob));
  }
  const int i = (x * 256 + threadIdx.x) * 4;
  const float4 xv = *(const float4*)(src + i);
  ushort4 p; p.x = f2bf(xv.x); p.y = f2bf(xv.y); p.z = f2bf(xv.z); p.w = f2bf(xv.w);
  *(ushort4*)(dst + i) = p;
}

// ---------------- GEMM core 128x128, BK=32, 4 waves 2x2 (m97 structure)
__device__ __forceinline__ void gemm_core128(const u16* __restrict__ A, const u16* __restrict__ Bt,
                                             int K, u16* As, u16* Bs, floatx4 acc[4][4],
                                             int m0, int n0) {
  const int tid = threadIdx.x;
  const int w = tid >> 6, l = tid & 63;
  const int lr = l & 15, lq = l >> 4;
  const int wm = (w >> 1) * 64, wn = (w & 1) * 64;

#pragma unroll
  for (int i = 0; i < 4; ++i)
#pragma unroll
    for (int j = 0; j < 4; ++j) acc[i][j] = (floatx4){0.f, 0.f, 0.f, 0.f};

  const int srow = w * 32 + (l >> 2);
  const int scol = (l & 3) * 8;
  const u16* ag = A + (size_t)(m0 + srow) * K + scol;
  const u16* bg = Bt + (size_t)(n0 + srow) * K + scol;
  u16* as0 = &As[w * 1024];
  u16* bs0 = &Bs[w * 1024];

  for (int k0 = 0; k0 < K; k0 += 32) {
    gll16(ag + k0, as0);
    gll16(ag + (size_t)16 * K + k0, as0 + 512);
    gll16(bg + k0, bs0);
    gll16(bg + (size_t)16 * K + k0, bs0 + 512);
    __syncthreads();
    short8 af[4], bfv[4];
#pragma unroll
    for (int i = 0; i < 4; ++i) af[i] = *(const short8*)&As[(wm + i * 16 + lr) * 32 + lq * 8];
#pragma unroll
    for (int j = 0; j < 4; ++j) bfv[j] = *(const short8*)&Bs[(wn + j * 16 + lr) * 32 + lq * 8];
    __builtin_amdgcn_s_setprio(1);
#pragma unroll
    for (int i = 0; i < 4; ++i)
#pragma unroll
      for (int j = 0; j < 4; ++j) acc[i][j] = MFMA16(af[i], bfv[j], acc[i][j]);
    __builtin_amdgcn_s_setprio(0);
    __syncthreads();
  }
}

// ---------------- GEMM core 64x128, BK=32 (out-projection: 512 blocks, 2/CU)
__device__ __forceinline__ void gemm_core64(const u16* __restrict__ A, const u16* __restrict__ Bt,
                                            int K, u16* As, u16* Bs, floatx4 acc[2][4],
                                            int m0, int n0) {
  const int tid = threadIdx.x;
  const int w = tid >> 6, l = tid & 63;
  const int lr = l & 15, lq = l >> 4;
  const int wm = (w >> 1) * 32, wn = (w & 1) * 64;

#pragma unroll
  for (int i = 0; i < 2; ++i)
#pragma unroll
    for (int j = 0; j < 4; ++j) acc[i][j] = (floatx4){0.f, 0.f, 0.f, 0.f};

  const int arow = w * 16 + (l >> 2);
  const int brow = w * 32 + (l >> 2);
  const int scol = (l & 3) * 8;
  const u16* ag = A + (size_t)(m0 + arow) * K + scol;
  const u16* bg = Bt + (size_t)(n0 + brow) * K + scol;
  u16* as0 = &As[w * 512];
  u16* bs0 = &Bs[w * 1024];

  for (int k0 = 0; k0 < K; k0 += 32) {
    gll16(ag + k0, as0);
    gll16(bg + k0, bs0);
    gll16(bg + (size_t)16 * K + k0, bs0 + 512);
    __syncthreads();
    short8 af[2], bfv[4];
#pragma unroll
    for (int i = 0; i < 2; ++i) af[i] = *(const short8*)&As[(wm + i * 16 + lr) * 32 + lq * 8];
#pragma unroll
    for (int j = 0; j < 4; ++j) bfv[j] = *(const short8*)&Bs[(wn + j * 16 + lr) * 32 + lq * 8];
    __builtin_amdgcn_s_setprio(1);
#pragma unroll
    for (int i = 0; i < 2; ++i)
#pragma unroll
      for (int j = 0; j < 4; ++j) acc[i][j] = MFMA16(af[i], bfv[j], acc[i][j]);
    __builtin_amdgcn_s_setprio(0);
    __syncthreads();
  }
}

// fused q/k/v projections (128x128 tile) + RoPE/pack (z=0 Q, z=1 K) or V-transpose (z=2)
__global__ __launch_bounds__(256) void gemm3_fused(
    const u16* __restrict__ A0, const u16* __restrict__ A1, const u16* __restrict__ A2,
    const u16* __restrict__ B0, const u16* __restrict__ B1, const u16* __restrict__ B2,
    const float* __restrict__ c0, const float* __restrict__ c1, const float* __restrict__ c2,
    u16* __restrict__ Qro, u16* __restrict__ Kro, u16* __restrict__ Vtr,
    const float2* __restrict__ tab) {
  __shared__ alignas(16) u16 As[128 * 32];
  __shared__ alignas(16) u16 Bs[128 * 32];
  const int z = blockIdx.z;
  const u16* A = z == 0 ? A0 : (z == 1 ? A1 : A2);
  const u16* Bt = z == 0 ? B0 : (z == 1 ? B1 : B2);
  const float* bias = z == 0 ? c0 : (z == 1 ? c1 : c2);
  const int m0 = blockIdx.y * 128, n0 = blockIdx.x * 128;

  floatx4 acc[4][4];
  gemm_core128(A, Bt, DD, As, Bs, acc, m0, n0);

  const int tid = threadIdx.x;
  const int w = tid >> 6, l = tid & 63;
  const int lr = l & 15, lq = l >> 4;
  const int wm = (w >> 1) * 64, wn = (w & 1) * 64;

  if (z == 2) {
    // V^T: Vt[((b*16+h)*64 + e)*SS + s], bias added, bf16
#pragma unroll
    for (int i = 0; i < 4; ++i) {
      const int row = m0 + wm + i * 16 + lq * 4;   // 4 consecutive s from here
      const int b = row >> 11, s = row & (SS - 1);
#pragma unroll
      for (int j = 0; j < 4; ++j) {
        const int col = n0 + wn + j * 16 + lr;
        const int h = col >> 6, e = col & 63;
        const float bv = bias[col];
        ushort4 pk;
        pk.x = f2bf(acc[i][j][0] + bv);
        pk.y = f2bf(acc[i][j][1] + bv);
        pk.z = f2bf(acc[i][j][2] + bv);
        pk.w = f2bf(acc[i][j][3] + bv);
        *(ushort4*)(Vtr + ((size_t)(b * HH + h) * DH + e) * SS + s) = pk;
      }
    }
  } else {
    u16* dst = z ? Kro : Qro;
#pragma unroll
    for (int i = 0; i < 4; ++i) {
#pragma unroll
      for (int j = 0; j < 4; ++j) {
        const int col = n0 + wn + j * 16 + lr;
        const int h = col >> 6, e = col & 63;
        const float bv = bias[col];
#pragma unroll
        for (int r = 0; r < 4; ++r) {
          const int row = m0 + wm + i * 16 + lq * 4 + r;
          const int b = row >> 11, s = row & (SS - 1);
          const float v = acc[i][j][r] + bv;
          const float p = __shfl_xor(v, 1);     // even/odd partner (col^1 <-> lane^1)
          const float2 sc = tab[s * 32 + (e >> 1)];
          const float ov = ((e & 1) == 0) ? (v * sc.x - p * sc.y)     //  x1*sin - x2*cos
                                          : (-p * sc.y - v * sc.x);   // -x1*cos - x2*sin
          dst[((size_t)(b * HH + h) * SS + s) * DH + e] = f2bf(ov);
        }
      }
    }
  }
}

// out-projection: C fp32 = A(bf16) * Bt^T + bias  (64x128 tile -> 512 blocks)
__global__ __launch_bounds__(256) void gemm_bt(const u16* __restrict__ A, const u16* __restrict__ Bt,
                                               const float* __restrict__ bias, float* __restrict__ C,
                                               int M, int N, int K) {
  __shared__ alignas(16) u16 As[64 * 32];
  __shared__ alignas(16) u16 Bs[128 * 32];
  const int m0 = blockIdx.y * 64, n0 = blockIdx.x * 128;
  floatx4 acc[2][4];
  gemm_core64(A, Bt, K, As, Bs, acc, m0, n0);

  const int tid = threadIdx.x;
  const int w = tid >> 6, l = tid & 63;
  const int lr = l & 15, lq = l >> 4;
  const int wm = (w >> 1) * 32, wn = (w & 1) * 64;
#pragma unroll
  for (int i = 0; i < 2; ++i) {
    const int row = m0 + wm + i * 16 + lq * 4;
#pragma unroll
    for (int j = 0; j < 4; ++j) {
      const int col = n0 + wn + j * 16 + lr;
      const float bv = bias[col];
      float* cp = C + (size_t)row * N + col;
#pragma unroll
      for (int r = 0; r < 4; ++r) cp[(size_t)r * N] = acc[i][j][r] + bv;
    }
  }
}

// ---------------- causal flash attention: 1 wave/block, NO LDS, NO barriers.
// All MFMA operands load global->register directly; 2048 blocks all co-resident.
// K double-buffered in regs (kA/kB); V loads issue right after QK (natural prefetch).
// S^T = mfma(K, Q): col=q (lane&31) -> lane-local softmax + 1 shfl(32); in-register P.
// XCD locality: bh = bid&31 -> XCD = bh%8 -> 4 (b,h) pairs = 2 MB K+V per XCD L2.
__global__ __launch_bounds__(64) void attn_fwd(const u16* __restrict__ Qr, const u16* __restrict__ Kr,
                                               const u16* __restrict__ Vt, u16* __restrict__ O) {
  const int bid = blockIdx.x;
  const int qi = 63 - (bid >> 5);              // heavy q-tiles first
  const int bh = bid & 31;
  const int l = threadIdx.x;
  const int ql = l & 31, hi = l >> 5;
  const int qw0 = qi * 32;                     // this wave's 32 q rows
  const u16* Qh = Qr + (size_t)bh * SS * DH;
  const u16* Kh = Kr + (size_t)bh * SS * DH;
  const u16* Vh = Vt + (size_t)bh * DH * SS;

  // Q B-fragments: lane holds q = qw0+ql, d = i*16 + hi*8 .. +7
  short8 qf[4];
#pragma unroll
  for (int i = 0; i < 4; ++i)
    qf[i] = *(const short8*)(Qh + (size_t)(qw0 + ql) * DH + i * 16 + hi * 8);

  floatx16 oacc[2];
#pragma unroll
  for (int dt = 0; dt < 2; ++dt)
#pragma unroll
    for (int r = 0; r < 16; ++r) oacc[dt][r] = 0.f;
  float mrun = -1e30f, lrun = 0.f;

  // per-lane operand bases
  const u16* kbase = Kh + (size_t)ql * DH + hi * 8;    // K[kv0+ql][i*16+hi*8 ..]
  const u16* vbase = Vh + (size_t)ql * SS + hi * 8;    // V^T[dt*32+ql][kv0+c*16 ..]

#define LOADK(kd, kv0)                                                      \
  do {                                                                      \
    const u16* kp_ = kbase + (size_t)(kv0) * DH;                            \
    kd[0] = *(const short8*)(kp_);                                          \
    kd[1] = *(const short8*)(kp_ + 16);                                     \
    kd[2] = *(const short8*)(kp_ + 32);                                     \
    kd[3] = *(const short8*)(kp_ + 48);                                     \
  } while (0)

  // COMPUTE one 32-kv tile using K regs kd; V loads issued post-QK (prefetch under softmax)
#define COMPUTE(kd, tt)                                                              \
  do {                                                                               \
    const int kv0_ = (tt) * 32;                                                      \
    floatx16 st;                                                                     \
    _Pragma("unroll") for (int r = 0; r < 16; ++r) st[r] = 0.f;                      \
    __builtin_amdgcn_s_setprio(1);                                                   \
    _Pragma("unroll") for (int i = 0; i < 4; ++i) st = MFMA32(kd[i], qf[i], st);     \
    __builtin_amdgcn_s_setprio(0);                                                   \
    short8 vf[4];                                                                    \
    {                                                                                \
      const u16* vp_ = vbase + kv0_;                                                 \
      vf[0] = *(const short8*)(vp_);                                                 \
      vf[1] = *(const short8*)(vp_ + 16);                                            \
      vf[2] = *(const short8*)(vp_ + (size_t)32 * SS);                               \
      vf[3] = *(const short8*)(vp_ + (size_t)32 * SS + 16);                          \
    }                                                                                \
    if ((tt) == T - 1) {  /* diagonal tile: mask kv > q */                           \
      _Pragma("unroll") for (int r = 0; r < 16; ++r) {                               \
        const int kv = (r & 3) + 8 * (r >> 2) + 4 * hi;                              \
        if (kv > ql) st[r] = -1e30f;                                                 \
      }                                                                              \
    }                                                                                \
    float m8[8];                                                                     \
    _Pragma("unroll") for (int r = 0; r < 8; ++r) m8[r] = fmaxf(st[r], st[r + 8]);   \
    float m4a = fmaxf(m8[0], m8[4]), m4b = fmaxf(m8[1], m8[5]);                      \
    float m4c = fmaxf(m8[2], m8[6]), m4d = fmaxf(m8[3], m8[7]);                      \
    float tmax = fmaxf(fmaxf(m4a, m4b), fmaxf(m4c, m4d));                            \
    tmax = fmaxf(tmax, __shfl_xor(tmax, 32));                                        \
    const float mn = fmaxf(mrun, tmax);                                              \
    const float sc = __expf(mrun - mn);                                              \
    mrun = mn;                                                                       \
    float ps = 0.f;                                                                  \
    _Pragma("unroll") for (int r = 0; r < 16; ++r) {                                 \
      const float p = __expf(st[r] - mn);                                            \
      st[r] = p;                                                                     \
      ps += p;                                                                       \
    }                                                                                \
    ps += __shfl_xor(ps, 32);                                                        \
    lrun = lrun * sc + ps;                                                           \
    _Pragma("unroll") for (int dt = 0; dt < 2; ++dt)                                 \
      _Pragma("unroll") for (int r = 0; r < 16; ++r) oacc[dt][r] *= sc;              \
    short8 pfrag[2];                                                                 \
    _Pragma("unroll") for (int c = 0; c < 2; ++c) {                                  \
      const int A0r = 2 * c, A1r = A0r + 1;                                          \
      const unsigned P00 = cvtpk(st[4 * A0r + 0], st[4 * A0r + 1]);                  \
      const unsigned P01 = cvtpk(st[4 * A0r + 2], st[4 * A0r + 3]);                  \
      const unsigned P10 = cvtpk(st[4 * A1r + 0], st[4 * A1r + 1]);                  \
      const unsigned P11 = cvtpk(st[4 * A1r + 2], st[4 * A1r + 3]);                  \
      const unsigned S0 = hi ? P00 : P10;                                            \
      const unsigned S1 = hi ? P01 : P11;                                            \
      const unsigned R0 = (unsigned)__shfl_xor((int)S0, 32);                         \
      const unsigned R1 = (unsigned)__shfl_xor((int)S1, 32);                         \
      union { unsigned u[4]; short8 s; } fd;                                         \
      fd.u[0] = hi ? R0 : P00;                                                       \
      fd.u[1] = hi ? R1 : P01;                                                       \
      fd.u[2] = hi ? P10 : R0;                                                       \
      fd.u[3] = hi ? P11 : R1;                                                       \
      pfrag[c] = fd.s;                                                               \
    }                                                                                \
    __builtin_amdgcn_s_setprio(1);                                                   \
    _Pragma("unroll") for (int dt = 0; dt < 2; ++dt)                                 \
      _Pragma("unroll") for (int c = 0; c < 2; ++c)                                  \
        oacc[dt] = MFMA32(vf[dt * 2 + c], pfrag[c], oacc[dt]);                       \
    __builtin_amdgcn_s_setprio(0);                                                   \
  } while (0)

  const int T = qi + 1;                        // 32-kv tiles up to (and incl.) the diagonal
  short8 kA[4], kB[4];
  LOADK(kA, 0);
  int t = 0;
  while (true) {
    if (t + 1 < T) LOADK(kB, (t + 1) * 32);    // prefetch next K while computing current
    COMPUTE(kA, t);
    ++t;
    if (t >= T) break;
    if (t + 1 < T) LOADK(kA, (t + 1) * 32);
    COMPUTE(kB, t);
    ++t;
    if (t >= T) break;
  }
#undef COMPUTE
#undef LOADK

  // ---- epilogue: lane owns q = qw0+ql; d = dt*32 + 8g + 4hi + 0..3
  const float inv = 1.0f / lrun;
  const int b = bh >> 4, h = bh & 15;
  u16* orow = O + ((size_t)(b * SS + qw0 + ql)) * DD + h * DH;
#pragma unroll
  for (int dt = 0; dt < 2; ++dt)
#pragma unroll
    for (int g = 0; g < 4; ++g) {
      ushort4 pk;
      pk.x = f2bf(oacc[dt][4 * g + 0] * inv);
      pk.y = f2bf(oacc[dt][4 * g + 1] * inv);
      pk.z = f2bf(oacc[dt][4 * g + 2] * inv);
      pk.w = f2bf(oacc[dt][4 * g + 3] * inv);
      *(ushort4*)(orow + dt * 32 + 8 * g + 4 * hi) = pk;
    }
}

extern "C" void kernel_launch(void* const* d_in, const int* in_sizes, int n_in,
                              void* d_out, int out_size, void* d_ws, size_t ws_size,
                              hipStream_t stream) {
  (void)in_sizes; (void)n_in; (void)out_size; (void)ws_size;
  const float* q  = (const float*)d_in[0];
  const float* k  = (const float*)d_in[1];
  const float* v  = (const float*)d_in[2];
  const float* Wq = (const float*)d_in[3];
  const float* bq = (const float*)d_in[4];
  const float* Wk = (const float*)d_in[5];
  const float* bk = (const float*)d_in[6];
  const float* Wv = (const float*)d_in[7];
  const float* bv = (const float*)d_in[8];
  const float* Wo = (const float*)d_in[9];
  const float* bo = (const float*)d_in[10];
  float* out = (float*)d_out;

  char* ws = (char*)d_ws;
  size_t off = 0;
  auto carve = [&](size_t bytes) { char* p = ws + off; off += (bytes + 255) & ~(size_t)255; return p; };
  u16* qb   = (u16*)carve((size_t)MM * DD * 2);
  u16* kb   = (u16*)carve((size_t)MM * DD * 2);
  u16* vb   = (u16*)carve((size_t)MM * DD * 2);
  u16* wqb  = (u16*)carve((size_t)DD * DD * 2);
  u16* wkb  = (u16*)carve((size_t)DD * DD * 2);
  u16* wvb  = (u16*)carve((size_t)DD * DD * 2);
  u16* wob  = (u16*)carve((size_t)DD * DD * 2);
  u16* Qro  = (u16*)carve((size_t)MM * DD * 2);
  u16* Kro  = (u16*)carve((size_t)MM * DD * 2);
  u16* Vtr  = (u16*)carve((size_t)MM * DD * 2);
  float2* tab = (float2*)carve((size_t)SS * 32 * 8);
  u16* Ob = qb;   // qb dead after gemm3_fused

  prep<<<256 + 3 * 4096 + 4 * 1024, 256, 0, stream>>>(q, k, v, Wq, Wk, Wv, Wo,
                                                      qb, kb, vb, wqb, wkb, wvb, wob, tab);
  gemm3_fused<<<dim3(DD / 128, MM / 128, 3), 256, 0, stream>>>(qb, kb, vb, wqb, wkb, wvb,
                                                               bq, bk, bv, Qro, Kro, Vtr, tab);
  attn_fwd<<<64 * BB * HH, 64, 0, stream>>>(Qro, Kro, Vtr, Ob);
  gemm_bt<<<dim3(DD / 128, MM / 64), 256, 0, stream>>>(Ob, wob, bo, out, MM, DD, DD);
}

// Round 10
// 271.492 us; speedup vs baseline: 1.0399x; 1.0399x over previous
//
#include <hip/hip_runtime.h>
#include <stdint.h>

// Problem constants
#define BB 2
#define SS 2048
#define DD 1024
#define HH 16
#define DH 64
#define MM 4096   // BB*SS

typedef __attribute__((ext_vector_type(8))) short short8;
typedef __attribute__((ext_vector_type(4))) float floatx4;
typedef __attribute__((ext_vector_type(16))) float floatx16;
typedef unsigned short u16;

#define MFMA16(a,b,c) __builtin_amdgcn_mfma_f32_16x16x32_bf16((a),(b),(c),0,0,0)
#define MFMA32(a,b,c) __builtin_amdgcn_mfma_f32_32x32x16_bf16((a),(b),(c),0,0,0)

__device__ __forceinline__ u16 f2bf(float f) {
  unsigned u = __float_as_uint(f);
  u += 0x7fffu + ((u >> 16) & 1u);
  return (u16)(u >> 16);
}

__device__ __forceinline__ unsigned cvtpk(float lo, float hi2) {
  unsigned r;
  asm("v_cvt_pk_bf16_f32 %0, %1, %2" : "=v"(r) : "v"(lo), "v"(hi2));
  return r;
}

__device__ __forceinline__ void gll16(const void* g, void* l) {
  __builtin_amdgcn_global_load_lds((const __attribute__((address_space(1))) void*)g,
                                   (__attribute__((address_space(3))) void*)l,
                                   16, 0, 0);
}

// ---------------- prep: sincos table + all fp32->bf16 conversions, one dispatch
__global__ __launch_bounds__(256) void prep(
    const float* __restrict__ q, const float* __restrict__ k, const float* __restrict__ v,
    const float* __restrict__ Wq, const float* __restrict__ Wk,
    const float* __restrict__ Wv, const float* __restrict__ Wo,
    u16* __restrict__ qb, u16* __restrict__ kb, u16* __restrict__ vb,
    u16* __restrict__ wqb, u16* __restrict__ wkb, u16* __restrict__ wvb, u16* __restrict__ wob,
    float2* __restrict__ tab) {
  int bid = blockIdx.x;
  if (bid < 256) {                       // sincos: tab[s*32+j] = (sin(s*inv_j), cos(s*inv_j))
    const int t = bid * 256 + threadIdx.x;
    const int s = t >> 5, j = t & 31;
    const float inv = expf(-(float)j * (0.125f * 2.302585092994046f)); // 10^(-j/8)
    const float a = (float)s * inv;
    tab[t] = make_float2(sinf(a), cosf(a));
    return;
  }
  bid -= 256;
  const float* src;
  u16* dst;
  int x;
  if (bid < 12288) {                     // q,k,v: 3 x 4096 blocks
    const int z = bid >> 12;
    x = bid & 4095;
    src = z == 0 ? q : (z == 1 ? k : v);
    dst = z == 0 ? qb : (z == 1 ? kb : vb);
  } else {                               // weights: 4 x 1024 blocks
    bid -= 12288;
    const int z = bid >> 10;
    x = bid & 1023;
    src = z == 0 ? Wq : (z == 1 ? Wk : (z == 2 ? Wv : Wo));
    dst = z == 0 ? wqb : (z == 1 ? wkb : (z == 2 ? wvb : wob));
  }
  const int i = (x * 256 + threadIdx.x) * 4;
  const float4 xv = *(const float4*)(src + i);
  ushort4 p; p.x = f2bf(xv.x); p.y = f2bf(xv.y); p.z = f2bf(xv.z); p.w = f2bf(xv.w);
  *(ushort4*)(dst + i) = p;
}

// ---------------- GEMM core 128x128, BK=32, 4 waves 2x2 (m97 structure)
__device__ __forceinline__ void gemm_core128(const u16* __restrict__ A, const u16* __restrict__ Bt,
                                             int K, u16* As, u16* Bs, floatx4 acc[4][4],
                                             int m0, int n0) {
  const int tid = threadIdx.x;
  const int w = tid >> 6, l = tid & 63;
  const int lr = l & 15, lq = l >> 4;
  const int wm = (w >> 1) * 64, wn = (w & 1) * 64;

#pragma unroll
  for (int i = 0; i < 4; ++i)
#pragma unroll
    for (int j = 0; j < 4; ++j) acc[i][j] = (floatx4){0.f, 0.f, 0.f, 0.f};

  const int srow = w * 32 + (l >> 2);
  const int scol = (l & 3) * 8;
  const u16* ag = A + (size_t)(m0 + srow) * K + scol;
  const u16* bg = Bt + (size_t)(n0 + srow) * K + scol;
  u16* as0 = &As[w * 1024];
  u16* bs0 = &Bs[w * 1024];

  for (int k0 = 0; k0 < K; k0 += 32) {
    gll16(ag + k0, as0);
    gll16(ag + (size_t)16 * K + k0, as0 + 512);
    gll16(bg + k0, bs0);
    gll16(bg + (size_t)16 * K + k0, bs0 + 512);
    __syncthreads();
    short8 af[4], bfv[4];
#pragma unroll
    for (int i = 0; i < 4; ++i) af[i] = *(const short8*)&As[(wm + i * 16 + lr) * 32 + lq * 8];
#pragma unroll
    for (int j = 0; j < 4; ++j) bfv[j] = *(const short8*)&Bs[(wn + j * 16 + lr) * 32 + lq * 8];
    __builtin_amdgcn_s_setprio(1);
#pragma unroll
    for (int i = 0; i < 4; ++i)
#pragma unroll
      for (int j = 0; j < 4; ++j) acc[i][j] = MFMA16(af[i], bfv[j], acc[i][j]);
    __builtin_amdgcn_s_setprio(0);
    __syncthreads();
  }
}

// ---------------- GEMM core 64x128, BK=32 (out-projection: 512 blocks, 2/CU)
__device__ __forceinline__ void gemm_core64(const u16* __restrict__ A, const u16* __restrict__ Bt,
                                            int K, u16* As, u16* Bs, floatx4 acc[2][4],
                                            int m0, int n0) {
  const int tid = threadIdx.x;
  const int w = tid >> 6, l = tid & 63;
  const int lr = l & 15, lq = l >> 4;
  const int wm = (w >> 1) * 32, wn = (w & 1) * 64;

#pragma unroll
  for (int i = 0; i < 2; ++i)
#pragma unroll
    for (int j = 0; j < 4; ++j) acc[i][j] = (floatx4){0.f, 0.f, 0.f, 0.f};

  const int arow = w * 16 + (l >> 2);
  const int brow = w * 32 + (l >> 2);
  const int scol = (l & 3) * 8;
  const u16* ag = A + (size_t)(m0 + arow) * K + scol;
  const u16* bg = Bt + (size_t)(n0 + brow) * K + scol;
  u16* as0 = &As[w * 512];
  u16* bs0 = &Bs[w * 1024];

  for (int k0 = 0; k0 < K; k0 += 32) {
    gll16(ag + k0, as0);
    gll16(bg + k0, bs0);
    gll16(bg + (size_t)16 * K + k0, bs0 + 512);
    __syncthreads();
    short8 af[2], bfv[4];
#pragma unroll
    for (int i = 0; i < 2; ++i) af[i] = *(const short8*)&As[(wm + i * 16 + lr) * 32 + lq * 8];
#pragma unroll
    for (int j = 0; j < 4; ++j) bfv[j] = *(const short8*)&Bs[(wn + j * 16 + lr) * 32 + lq * 8];
    __builtin_amdgcn_s_setprio(1);
#pragma unroll
    for (int i = 0; i < 2; ++i)
#pragma unroll
      for (int j = 0; j < 4; ++j) acc[i][j] = MFMA16(af[i], bfv[j], acc[i][j]);
    __builtin_amdgcn_s_setprio(0);
    __syncthreads();
  }
}

// fused q/k/v projections (128x128 tile) + RoPE/pack (z=0 Q, z=1 K) or V-transpose (z=2)
__global__ __launch_bounds__(256) void gemm3_fused(
    const u16* __restrict__ A0, const u16* __restrict__ A1, const u16* __restrict__ A2,
    const u16* __restrict__ B0, const u16* __restrict__ B1, const u16* __restrict__ B2,
    const float* __restrict__ c0, const float* __restrict__ c1, const float* __restrict__ c2,
    u16* __restrict__ Qro, u16* __restrict__ Kro, u16* __restrict__ Vtr,
    const float2* __restrict__ tab) {
  __shared__ alignas(16) u16 As[128 * 32];
  __shared__ alignas(16) u16 Bs[128 * 32];
  const int z = blockIdx.z;
  const u16* A = z == 0 ? A0 : (z == 1 ? A1 : A2);
  const u16* Bt = z == 0 ? B0 : (z == 1 ? B1 : B2);
  const float* bias = z == 0 ? c0 : (z == 1 ? c1 : c2);
  const int m0 = blockIdx.y * 128, n0 = blockIdx.x * 128;

  floatx4 acc[4][4];
  gemm_core128(A, Bt, DD, As, Bs, acc, m0, n0);

  const int tid = threadIdx.x;
  const int w = tid >> 6, l = tid & 63;
  const int lr = l & 15, lq = l >> 4;
  const int wm = (w >> 1) * 64, wn = (w & 1) * 64;

  if (z == 2) {
    // V^T: Vt[((b*16+h)*64 + e)*SS + s], bias added, bf16
#pragma unroll
    for (int i = 0; i < 4; ++i) {
      const int row = m0 + wm + i * 16 + lq * 4;   // 4 consecutive s from here
      const int b = row >> 11, s = row & (SS - 1);
#pragma unroll
      for (int j = 0; j < 4; ++j) {
        const int col = n0 + wn + j * 16 + lr;
        const int h = col >> 6, e = col & 63;
        const float bv = bias[col];
        ushort4 pk;
        pk.x = f2bf(acc[i][j][0] + bv);
        pk.y = f2bf(acc[i][j][1] + bv);
        pk.z = f2bf(acc[i][j][2] + bv);
        pk.w = f2bf(acc[i][j][3] + bv);
        *(ushort4*)(Vtr + ((size_t)(b * HH + h) * DH + e) * SS + s) = pk;
      }
    }
  } else {
    u16* dst = z ? Kro : Qro;
#pragma unroll
    for (int i = 0; i < 4; ++i) {
#pragma unroll
      for (int j = 0; j < 4; ++j) {
        const int col = n0 + wn + j * 16 + lr;
        const int h = col >> 6, e = col & 63;
        const float bv = bias[col];
#pragma unroll
        for (int r = 0; r < 4; ++r) {
          const int row = m0 + wm + i * 16 + lq * 4 + r;
          const int b = row >> 11, s = row & (SS - 1);
          const float v = acc[i][j][r] + bv;
          const float p = __shfl_xor(v, 1);     // even/odd partner (col^1 <-> lane^1)
          const float2 sc = tab[s * 32 + (e >> 1)];
          const float ov = ((e & 1) == 0) ? (v * sc.x - p * sc.y)     //  x1*sin - x2*cos
                                          : (-p * sc.y - v * sc.x);   // -x1*cos - x2*sin
          dst[((size_t)(b * HH + h) * SS + s) * DH + e] = f2bf(ov);
        }
      }
    }
  }
}

// out-projection: C fp32 = A(bf16) * Bt^T + bias  (64x128 tile -> 512 blocks)
__global__ __launch_bounds__(256) void gemm_bt(const u16* __restrict__ A, const u16* __restrict__ Bt,
                                               const float* __restrict__ bias, float* __restrict__ C,
                                               int M, int N, int K) {
  __shared__ alignas(16) u16 As[64 * 32];
  __shared__ alignas(16) u16 Bs[128 * 32];
  const int m0 = blockIdx.y * 64, n0 = blockIdx.x * 128;
  floatx4 acc[2][4];
  gemm_core64(A, Bt, K, As, Bs, acc, m0, n0);

  const int tid = threadIdx.x;
  const int w = tid >> 6, l = tid & 63;
  const int lr = l & 15, lq = l >> 4;
  const int wm = (w >> 1) * 32, wn = (w & 1) * 64;
#pragma unroll
  for (int i = 0; i < 2; ++i) {
    const int row = m0 + wm + i * 16 + lq * 4;
#pragma unroll
    for (int j = 0; j < 4; ++j) {
      const int col = n0 + wn + j * 16 + lr;
      const float bv = bias[col];
      float* cp = C + (size_t)row * N + col;
#pragma unroll
      for (int r = 0; r < 4; ++r) cp[(size_t)r * N] = acc[i][j][r] + bv;
    }
  }
}

// ---------------- causal flash attention: 2-way KV-split, zero staging LDS, no vmcnt asm.
// Block = 2 waves sharing one (q-tile, head): wave0 does kv tiles [0,ceil(T/2)),
// wave1 [ceil(T/2),T) incl. masked diagonal. Private (m,l,O) per wave; one LDS merge.
// 2048 blocks x 2 waves = 4096 waves @ ~108 VGPR -> 4 waves/SIMD: entire grid resident.
// S^T = mfma(K, Q): col=q (lane&31) -> lane-local softmax + 1 shfl(32); in-register P.
__global__ __launch_bounds__(128) void attn_fwd(const u16* __restrict__ Qr, const u16* __restrict__ Kr,
                                                const u16* __restrict__ Vt, u16* __restrict__ O) {
  __shared__ float Ms[64], Ls[64];
  __shared__ float Os[64][33];                 // +1 pad: conflict-free lane-major access
  const int bid = blockIdx.x;
  const int qi = 63 - (bid >> 5);              // heavy q-tiles first
  const int bh = bid & 31;
  const int w = threadIdx.x >> 6;
  const int l = threadIdx.x & 63;
  const int ql = l & 31, hi = l >> 5;
  const int qw0 = qi * 32;                     // this block's 32 q rows
  const u16* Qh = Qr + (size_t)bh * SS * DH;
  const u16* Kh = Kr + (size_t)bh * SS * DH;
  const u16* Vh = Vt + (size_t)bh * DH * SS;

  // Q B-fragments: lane holds q = qw0+ql, d = i*16 + hi*8 .. +7
  short8 qf[4];
#pragma unroll
  for (int i = 0; i < 4; ++i)
    qf[i] = *(const short8*)(Qh + (size_t)(qw0 + ql) * DH + i * 16 + hi * 8);

  floatx16 oacc[2];
#pragma unroll
  for (int dt = 0; dt < 2; ++dt)
#pragma unroll
    for (int r = 0; r < 16; ++r) oacc[dt][r] = 0.f;
  float mrun = -1e30f, lrun = 0.f;

  // per-lane operand bases
  const u16* kbase = Kh + (size_t)ql * DH + hi * 8;    // K[kv0+ql][i*16+hi*8 ..]
  const u16* vbase = Vh + (size_t)ql * SS + hi * 8;    // V^T[dt*32+ql][kv0+c*16 ..]

#define LOADK(kd, kv0)                                                      \
  do {                                                                      \
    const u16* kp_ = kbase + (size_t)(kv0) * DH;                            \
    kd[0] = *(const short8*)(kp_);                                          \
    kd[1] = *(const short8*)(kp_ + 16);                                     \
    kd[2] = *(const short8*)(kp_ + 32);                                     \
    kd[3] = *(const short8*)(kp_ + 48);                                     \
  } while (0)

#define COMPUTE(kd, tt)                                                              \
  do {                                                                               \
    const int kv0_ = (tt) * 32;                                                      \
    floatx16 st;                                                                     \
    _Pragma("unroll") for (int r = 0; r < 16; ++r) st[r] = 0.f;                      \
    __builtin_amdgcn_s_setprio(1);                                                   \
    _Pragma("unroll") for (int i = 0; i < 4; ++i) st = MFMA32(kd[i], qf[i], st);     \
    __builtin_amdgcn_s_setprio(0);                                                   \
    short8 vf[4];                                                                    \
    {                                                                                \
      const u16* vp_ = vbase + kv0_;                                                 \
      vf[0] = *(const short8*)(vp_);                                                 \
      vf[1] = *(const short8*)(vp_ + 16);                                            \
      vf[2] = *(const short8*)(vp_ + (size_t)32 * SS);                               \
      vf[3] = *(const short8*)(vp_ + (size_t)32 * SS + 16);                          \
    }                                                                                \
    if ((tt) == T - 1) {  /* diagonal tile: mask kv > q */                           \
      _Pragma("unroll") for (int r = 0; r < 16; ++r) {                               \
        const int kv = (r & 3) + 8 * (r >> 2) + 4 * hi;                              \
        if (kv > ql) st[r] = -1e30f;                                                 \
      }                                                                              \
    }                                                                                \
    float m8[8];                                                                     \
    _Pragma("unroll") for (int r = 0; r < 8; ++r) m8[r] = fmaxf(st[r], st[r + 8]);   \
    float m4a = fmaxf(m8[0], m8[4]), m4b = fmaxf(m8[1], m8[5]);                      \
    float m4c = fmaxf(m8[2], m8[6]), m4d = fmaxf(m8[3], m8[7]);                      \
    float tmax = fmaxf(fmaxf(m4a, m4b), fmaxf(m4c, m4d));                            \
    tmax = fmaxf(tmax, __shfl_xor(tmax, 32));                                        \
    const float mn = fmaxf(mrun, tmax);                                              \
    const float sc = __expf(mrun - mn);                                              \
    mrun = mn;                                                                       \
    float ps = 0.f;                                                                  \
    _Pragma("unroll") for (int r = 0; r < 16; ++r) {                                 \
      const float p = __expf(st[r] - mn);                                            \
      st[r] = p;                                                                     \
      ps += p;                                                                       \
    }                                                                                \
    ps += __shfl_xor(ps, 32);                                                        \
    lrun = lrun * sc + ps;                                                           \
    _Pragma("unroll") for (int dt = 0; dt < 2; ++dt)                                 \
      _Pragma("unroll") for (int r = 0; r < 16; ++r) oacc[dt][r] *= sc;              \
    short8 pfrag[2];                                                                 \
    _Pragma("unroll") for (int c = 0; c < 2; ++c) {                                  \
      const int A0r = 2 * c, A1r = A0r + 1;                                          \
      const unsigned P00 = cvtpk(st[4 * A0r + 0], st[4 * A0r + 1]);                  \
      const unsigned P01 = cvtpk(st[4 * A0r + 2], st[4 * A0r + 3]);                  \
      const unsigned P10 = cvtpk(st[4 * A1r + 0], st[4 * A1r + 1]);                  \
      const unsigned P11 = cvtpk(st[4 * A1r + 2], st[4 * A1r + 3]);                  \
      const unsigned S0 = hi ? P00 : P10;                                            \
      const unsigned S1 = hi ? P01 : P11;                                            \
      const unsigned R0 = (unsigned)__shfl_xor((int)S0, 32);                         \
      const unsigned R1 = (unsigned)__shfl_xor((int)S1, 32);                         \
      union { unsigned u[4]; short8 s; } fd;                                         \
      fd.u[0] = hi ? R0 : P00;                                                       \
      fd.u[1] = hi ? R1 : P01;                                                       \
      fd.u[2] = hi ? P10 : R0;                                                       \
      fd.u[3] = hi ? P11 : R1;                                                       \
      pfrag[c] = fd.s;                                                               \
    }                                                                                \
    __builtin_amdgcn_s_setprio(1);                                                   \
    _Pragma("unroll") for (int dt = 0; dt < 2; ++dt)                                 \
      _Pragma("unroll") for (int c = 0; c < 2; ++c)                                  \
        oacc[dt] = MFMA32(vf[dt * 2 + c], pfrag[c], oacc[dt]);                       \
    __builtin_amdgcn_s_setprio(0);                                                   \
  } while (0)

  const int T = qi + 1;                        // total 32-kv tiles incl. diagonal
  const int Th = (T + 1) >> 1;                 // wave0: [0,Th), wave1: [Th,T)
  const int tbeg = w ? Th : 0;
  const int tend = w ? T : Th;

  if (tbeg < tend) {
    short8 kA[4], kB[4];
    LOADK(kA, tbeg * 32);
    int t = tbeg;
    while (true) {
      if (t + 1 < tend) LOADK(kB, (t + 1) * 32);
      COMPUTE(kA, t);
      ++t;
      if (t >= tend) break;
      if (t + 1 < tend) LOADK(kA, (t + 1) * 32);
      COMPUTE(kB, t);
      ++t;
      if (t >= tend) break;
    }
  }
#undef COMPUTE
#undef LOADK

  // ---- merge the two waves' partial (m, l, O) and write out (wave 1)
  if (w == 0) {
    Ms[l] = mrun;
    Ls[l] = lrun;
#pragma unroll
    for (int dt = 0; dt < 2; ++dt)
#pragma unroll
      for (int r = 0; r < 16; ++r) Os[l][dt * 16 + r] = oacc[dt][r];
  }
  __syncthreads();
  if (w == 1) {
    const float m1 = Ms[l], l1 = Ls[l];
    const float mm = fmaxf(m1, mrun);
    const float a1 = __expf(m1 - mm);
    const float a2 = __expf(mrun - mm);
    const float inv = 1.0f / (l1 * a1 + lrun * a2);
    const int b = bh >> 4, h = bh & 15;
    u16* orow = O + ((size_t)(b * SS + qw0 + ql)) * DD + h * DH;
#pragma unroll
    for (int dt = 0; dt < 2; ++dt)
#pragma unroll
      for (int g = 0; g < 4; ++g) {
        ushort4 pk;
        pk.x = f2bf((Os[l][dt * 16 + 4 * g + 0] * a1 + oacc[dt][4 * g + 0] * a2) * inv);
        pk.y = f2bf((Os[l][dt * 16 + 4 * g + 1] * a1 + oacc[dt][4 * g + 1] * a2) * inv);
        pk.z = f2bf((Os[l][dt * 16 + 4 * g + 2] * a1 + oacc[dt][4 * g + 2] * a2) * inv);
        pk.w = f2bf((Os[l][dt * 16 + 4 * g + 3] * a1 + oacc[dt][4 * g + 3] * a2) * inv);
        *(ushort4*)(orow + dt * 32 + 8 * g + 4 * hi) = pk;
      }
  }
}

extern "C" void kernel_launch(void* const* d_in, const int* in_sizes, int n_in,
                              void* d_out, int out_size, void* d_ws, size_t ws_size,
                              hipStream_t stream) {
  (void)in_sizes; (void)n_in; (void)out_size; (void)ws_size;
  const float* q  = (const float*)d_in[0];
  const float* k  = (const float*)d_in[1];
  const float* v  = (const float*)d_in[2];
  const float* Wq = (const float*)d_in[3];
  const float* bq = (const float*)d_in[4];
  const float* Wk = (const float*)d_in[5];
  const float* bk = (const float*)d_in[6];
  const float* Wv = (const float*)d_in[7];
  const float* bv = (const float*)d_in[8];
  const float* Wo = (const float*)d_in[9];
  const float* bo = (const float*)d_in[10];
  float* out = (float*)d_out;

  char* ws = (char*)d_ws;
  size_t off = 0;
  auto carve = [&](size_t bytes) { char* p = ws + off; off += (bytes + 255) & ~(size_t)255; return p; };
  u16* qb   = (u16*)carve((size_t)MM * DD * 2);
  u16* kb   = (u16*)carve((size_t)MM * DD * 2);
  u16* vb   = (u16*)carve((size_t)MM * DD * 2);
  u16* wqb  = (u16*)carve((size_t)DD * DD * 2);
  u16* wkb  = (u16*)carve((size_t)DD * DD * 2);
  u16* wvb  = (u16*)carve((size_t)DD * DD * 2);
  u16* wob  = (u16*)carve((size_t)DD * DD * 2);
  u16* Qro  = (u16*)carve((size_t)MM * DD * 2);
  u16* Kro  = (u16*)carve((size_t)MM * DD * 2);
  u16* Vtr  = (u16*)carve((size_t)MM * DD * 2);
  float2* tab = (float2*)carve((size_t)SS * 32 * 8);
  u16* Ob = qb;   // qb dead after gemm3_fused

  prep<<<256 + 3 * 4096 + 4 * 1024, 256, 0, stream>>>(q, k, v, Wq, Wk, Wv, Wo,
                                                      qb, kb, vb, wqb, wkb, wvb, wob, tab);
  gemm3_fused<<<dim3(DD / 128, MM / 128, 3), 256, 0, stream>>>(qb, kb, vb, wqb, wkb, wvb,
                                                               bq, bk, bv, Qro, Kro, Vtr, tab);
  attn_fwd<<<64 * BB * HH, 128, 0, stream>>>(Qro, Kro, Vtr, Ob);
  gemm_bt<<<dim3(DD / 128, MM / 64), 256, 0, stream>>>(Ob, wob, bo, out, MM, DD, DD);
}